// Round 1
// baseline (127.046 us; speedup 1.0000x reference)
//
#include <hip/hip_runtime.h>

#define DIMS 128
#define KTOP 16
#define SMAX 2048   // max MAXG supported in LDS (harness uses 2048)

__global__ __launch_bounds__(256)
void tabera_topk_kernel(const float* __restrict__ query,
                        const float* __restrict__ keys,
                        const float* __restrict__ vals,
                        const float* __restrict__ labels,
                        const int*   __restrict__ hard_assign,
                        const int*   __restrict__ cached_groups,
                        const int*   __restrict__ group_sizes,
                        float* __restrict__ out,
                        int B, int N, int P, int MAXG)
{
    const int b   = blockIdx.x;
    const int t   = threadIdx.x;
    const int sub = t & 15;   // lane within candidate group (covers 8 floats of D)
    const int cg  = t >> 4;   // candidate-group id 0..15

    __shared__ float s_sim[SMAX];
    __shared__ unsigned long long s_red[4];
    __shared__ unsigned long long s_win;
    __shared__ int s_wing[KTOP];

    const int p   = hard_assign[b];
    const int grp = group_sizes[p];
    const bool normal = (grp >= KTOP);
    const int* gptr = cached_groups + (size_t)p * MAXG;

    // pad sim with -inf (in case MAXG < SMAX)
    #pragma unroll
    for (int j = 0; j < SMAX / 256; ++j) s_sim[j * 256 + t] = -3.0e38f;

    // query fragment: 8 floats per sub-lane, kept in registers for all iters
    const float* qrow = query + (size_t)b * DIMS + sub * 8;
    float4 q0 = *(const float4*)(qrow);
    float4 q1 = *(const float4*)(qrow + 4);

    float qss = q0.x*q0.x + q0.y*q0.y + q0.z*q0.z + q0.w*q0.w
              + q1.x*q1.x + q1.y*q1.y + q1.z*q1.z + q1.w*q1.w;
    #pragma unroll
    for (int m = 1; m < 16; m <<= 1) qss += __shfl_xor(qss, m, 64);
    const float inv_q = 1.0f / fmaxf(sqrtf(qss), 1e-12f);

    __syncthreads();

    // score all candidates: 16 candidates per iteration (one per cg group)
    const int iters = (MAXG + 15) / 16;
    for (int i = 0; i < iters; ++i) {
        const int g  = i * 16 + cg;
        const bool inb = (g < MAXG);
        const int cand = inb ? gptr[g] : -1;
        const int safe = cand < 0 ? 0 : cand;
        const float* kr = keys + (size_t)safe * DIMS + sub * 8;
        float4 k0 = *(const float4*)(kr);
        float4 k1 = *(const float4*)(kr + 4);
        float dt = q0.x*k0.x + q0.y*k0.y + q0.z*k0.z + q0.w*k0.w
                 + q1.x*k1.x + q1.y*k1.y + q1.z*k1.z + q1.w*k1.w;
        float ks = k0.x*k0.x + k0.y*k0.y + k0.z*k0.z + k0.w*k0.w
                 + k1.x*k1.x + k1.y*k1.y + k1.z*k1.z + k1.w*k1.w;
        #pragma unroll
        for (int m = 1; m < 16; m <<= 1) {
            dt += __shfl_xor(dt, m, 64);
            ks += __shfl_xor(ks, m, 64);
        }
        if (sub == 0 && inb) {
            s_sim[g] = (cand >= 0)
                ? dt * inv_q * (1.0f / fmaxf(sqrtf(ks), 1e-12f))
                : -1.0e9f;
        }
    }
    __syncthreads();

    // pack (value, slot) into u64: larger value wins; ties -> smaller slot wins
    unsigned long long mk[SMAX / 256];
    #pragma unroll
    for (int j = 0; j < SMAX / 256; ++j) {
        const int g = t * (SMAX / 256) + j;
        unsigned u = __float_as_uint(s_sim[g]);
        u = (u & 0x80000000u) ? ~u : (u | 0x80000000u);
        mk[j] = ((unsigned long long)u << 32) | (unsigned)(0xFFFFFFFFu - (unsigned)g);
    }

    // 16 rounds of block-wide argmax
    for (int s = 0; s < KTOP; ++s) {
        unsigned long long m = mk[0];
        #pragma unroll
        for (int j = 1; j < SMAX / 256; ++j) m = (mk[j] > m) ? mk[j] : m;
        #pragma unroll
        for (int off = 1; off < 64; off <<= 1) {
            unsigned long long o = __shfl_xor(m, off, 64);
            m = (o > m) ? o : m;
        }
        if ((t & 63) == 0) s_red[t >> 6] = m;
        __syncthreads();
        if (t == 0) {
            unsigned long long w = s_red[0];
            if (s_red[1] > w) w = s_red[1];
            if (s_red[2] > w) w = s_red[2];
            if (s_red[3] > w) w = s_red[3];
            s_win = w;
            s_wing[s] = (int)(0xFFFFFFFFu - (unsigned)(w & 0xFFFFFFFFull));
        }
        __syncthreads();
        const unsigned long long w = s_win;
        #pragma unroll
        for (int j = 0; j < SMAX / 256; ++j) if (mk[j] == w) mk[j] = 0ull;
    }

    // outputs: group cg handles winner #cg
    const int g    = s_wing[cg];
    const int cand = gptr[g];
    const int idx  = cand < 0 ? 0 : cand;

    const size_t BK = (size_t)B * KTOP;
    float* out_nk = out;
    float* out_nv = out + BK * DIMS;
    float* out_nl = out + 2 * BK * DIMS;
    float* out_id = out_nl + BK;

    const size_t od = ((size_t)b * KTOP + cg) * DIMS + sub * 8;
    if (normal) {
        const float* kr = keys + (size_t)idx * DIMS + sub * 8;
        const float* vr = vals + (size_t)idx * DIMS + sub * 8;
        *(float4*)(out_nk + od)     = *(const float4*)(kr);
        *(float4*)(out_nk + od + 4) = *(const float4*)(kr + 4);
        *(float4*)(out_nv + od)     = *(const float4*)(vr);
        *(float4*)(out_nv + od + 4) = *(const float4*)(vr + 4);
        if (sub == 0) {
            out_nl[(size_t)b * KTOP + cg] = labels[idx];
            out_id[(size_t)b * KTOP + cg] = (float)idx;  // int index stored as f32 value
        }
    } else {
        const float4 z = make_float4(0.f, 0.f, 0.f, 0.f);
        *(float4*)(out_nk + od)     = z;
        *(float4*)(out_nk + od + 4) = z;
        *(float4*)(out_nv + od)     = z;
        *(float4*)(out_nv + od + 4) = z;
        if (sub == 0) {
            out_nl[(size_t)b * KTOP + cg] = 0.0f;
            out_id[(size_t)b * KTOP + cg] = 0.0f;
        }
    }
}

extern "C" void kernel_launch(void* const* d_in, const int* in_sizes, int n_in,
                              void* d_out, int out_size, void* d_ws, size_t ws_size,
                              hipStream_t stream) {
    const float* query  = (const float*)d_in[0];
    const float* keys   = (const float*)d_in[1];
    const float* vals   = (const float*)d_in[2];
    const float* labels = (const float*)d_in[3];
    const int* hard_assign   = (const int*)d_in[4];
    const int* cached_groups = (const int*)d_in[5];
    const int* group_sizes   = (const int*)d_in[6];

    const int B = in_sizes[0] / DIMS;
    const int N = in_sizes[1] / DIMS;
    const int P = in_sizes[6];
    const int MAXG = in_sizes[5] / P;

    tabera_topk_kernel<<<B, 256, 0, stream>>>(
        query, keys, vals, labels, hard_assign, cached_groups, group_sizes,
        (float*)d_out, B, N, P, MAXG);
}

// Round 2
// 95.258 us; speedup vs baseline: 1.3337x; 1.3337x over previous
//
#include <hip/hip_runtime.h>

#define DIMS 128
#define KTOP 16
#define SMAX 2048   // max MAXG supported by top-k kernel
#define SLICES 8

__device__ __forceinline__ float dot8(float4 a0, float4 a1, float4 b0, float4 b1) {
    return a0.x*b0.x + a0.y*b0.y + a0.z*b0.z + a0.w*b0.w
         + a1.x*b1.x + a1.y*b1.y + a1.z*b1.z + a1.w*b1.w;
}

// ---------------- Kernel A: inverse L2 norm of every key row ----------------
__global__ __launch_bounds__(256)
void key_norm_kernel(const float* __restrict__ keys, float* __restrict__ inv_norm, int N)
{
    const int t = threadIdx.x, sub = t & 15, cg = t >> 4;
    const int row = blockIdx.x * 16 + cg;
    if (row >= N) return;
    const float* kr = keys + (size_t)row * DIMS + sub * 8;
    float4 k0 = *(const float4*)(kr);
    float4 k1 = *(const float4*)(kr + 4);
    float ks = dot8(k0, k1, k0, k1);
    #pragma unroll
    for (int m = 1; m < 16; m <<= 1) ks += __shfl_xor(ks, m, 64);
    if (sub == 0) inv_norm[row] = 1.0f / fmaxf(sqrtf(ks), 1e-12f);
}

// ---------------- Kernel B: score one 256-candidate slice per block ----------
__global__ __launch_bounds__(256)
void score_kernel(const float* __restrict__ query,
                  const float* __restrict__ keys,
                  const int*   __restrict__ hard_assign,
                  const int*   __restrict__ cached_groups,
                  const float* __restrict__ inv_norm,
                  float* __restrict__ sims,
                  int MAXG, int slice_c)
{
    const int b = blockIdx.x / SLICES;
    const int s = blockIdx.x % SLICES;
    const int t = threadIdx.x, sub = t & 15, cg = t >> 4;

    __shared__ int s_g[512];

    const int p = hard_assign[b];
    const int base = s * slice_c;
    const int* gp = cached_groups + (size_t)p * MAXG + base;

    for (int j = t; j < slice_c; j += 256)
        s_g[j] = (base + j < MAXG) ? gp[j] : -1;

    // query fragment in registers (q-normalization dropped: positive per-query
    // scale cannot change the top-k ordering)
    const float* qrow = query + (size_t)b * DIMS + sub * 8;
    const float4 q0 = *(const float4*)(qrow);
    const float4 q1 = *(const float4*)(qrow + 4);

    __syncthreads();

    float* simrow = sims + (size_t)b * MAXG + base;
    const int iters = slice_c / 16;
    #pragma unroll 4
    for (int i = 0; i < iters; ++i) {
        const int g = i * 16 + cg;
        const int cand = s_g[g];
        const int safe = cand < 0 ? 0 : cand;
        const float* kr = keys + (size_t)safe * DIMS + sub * 8;
        const float4 k0 = *(const float4*)(kr);
        const float4 k1 = *(const float4*)(kr + 4);
        const float invk = inv_norm[safe];
        float dt = dot8(q0, q1, k0, k1);
        #pragma unroll
        for (int m = 1; m < 16; m <<= 1) dt += __shfl_xor(dt, m, 64);
        if (sub == 0 && base + g < MAXG)
            simrow[g] = (cand >= 0) ? dt * invk : -1.0e9f;
    }
}

// ---------------- Kernel C: top-16 per query + output gather ----------------
__global__ __launch_bounds__(256)
void topk_gather_kernel(const float* __restrict__ keys,
                        const float* __restrict__ vals,
                        const float* __restrict__ labels,
                        const int*   __restrict__ hard_assign,
                        const int*   __restrict__ cached_groups,
                        const int*   __restrict__ group_sizes,
                        const float* __restrict__ sims,
                        float* __restrict__ out,
                        int B, int MAXG)
{
    const int b = blockIdx.x, t = threadIdx.x;
    const int sub = t & 15, cg = t >> 4;

    __shared__ unsigned long long s_red[4];
    __shared__ unsigned long long s_win;
    __shared__ int s_wing[KTOP];

    const int p = hard_assign[b];
    const int grp = group_sizes[p];
    const bool normal = (grp >= KTOP);
    const int* gptr = cached_groups + (size_t)p * MAXG;
    const float* simrow = sims + (size_t)b * MAXG;

    // pack (value, slot): larger value wins; ties -> smaller slot wins
    unsigned long long mk[SMAX / 256];
    #pragma unroll
    for (int j = 0; j < SMAX / 256; ++j) {
        const int g = j * 256 + t;                 // coalesced read
        const float v = (g < MAXG) ? simrow[g] : -3.0e38f;
        unsigned u = __float_as_uint(v);
        u = (u & 0x80000000u) ? ~u : (u | 0x80000000u);
        mk[j] = ((unsigned long long)u << 32) | (unsigned)(0xFFFFFFFFu - (unsigned)g);
    }

    for (int s = 0; s < KTOP; ++s) {
        unsigned long long m = mk[0];
        #pragma unroll
        for (int j = 1; j < SMAX / 256; ++j) m = (mk[j] > m) ? mk[j] : m;
        #pragma unroll
        for (int off = 1; off < 64; off <<= 1) {
            unsigned long long o = __shfl_xor(m, off, 64);
            m = (o > m) ? o : m;
        }
        if ((t & 63) == 0) s_red[t >> 6] = m;
        __syncthreads();
        if (t == 0) {
            unsigned long long w = s_red[0];
            if (s_red[1] > w) w = s_red[1];
            if (s_red[2] > w) w = s_red[2];
            if (s_red[3] > w) w = s_red[3];
            s_win = w;
            s_wing[s] = (int)(0xFFFFFFFFu - (unsigned)(w & 0xFFFFFFFFull));
        }
        __syncthreads();
        const unsigned long long w = s_win;
        #pragma unroll
        for (int j = 0; j < SMAX / 256; ++j) if (mk[j] == w) mk[j] = 0ull;
    }

    // outputs: group cg handles winner #cg
    const int g    = s_wing[cg];
    const int cand = gptr[g];
    const int idx  = cand < 0 ? 0 : cand;

    const size_t BK = (size_t)B * KTOP;
    float* out_nk = out;
    float* out_nv = out + BK * DIMS;
    float* out_nl = out + 2 * BK * DIMS;
    float* out_id = out_nl + BK;

    const size_t od = ((size_t)b * KTOP + cg) * DIMS + sub * 8;
    if (normal) {
        const float* kr = keys + (size_t)idx * DIMS + sub * 8;
        const float* vr = vals + (size_t)idx * DIMS + sub * 8;
        *(float4*)(out_nk + od)     = *(const float4*)(kr);
        *(float4*)(out_nk + od + 4) = *(const float4*)(kr + 4);
        *(float4*)(out_nv + od)     = *(const float4*)(vr);
        *(float4*)(out_nv + od + 4) = *(const float4*)(vr + 4);
        if (sub == 0) {
            out_nl[(size_t)b * KTOP + cg] = labels[idx];
            out_id[(size_t)b * KTOP + cg] = (float)idx;
        }
    } else {
        const float4 z = make_float4(0.f, 0.f, 0.f, 0.f);
        *(float4*)(out_nk + od)     = z;
        *(float4*)(out_nk + od + 4) = z;
        *(float4*)(out_nv + od)     = z;
        *(float4*)(out_nv + od + 4) = z;
        if (sub == 0) {
            out_nl[(size_t)b * KTOP + cg] = 0.0f;
            out_id[(size_t)b * KTOP + cg] = 0.0f;
        }
    }
}

extern "C" void kernel_launch(void* const* d_in, const int* in_sizes, int n_in,
                              void* d_out, int out_size, void* d_ws, size_t ws_size,
                              hipStream_t stream) {
    const float* query  = (const float*)d_in[0];
    const float* keys   = (const float*)d_in[1];
    const float* vals   = (const float*)d_in[2];
    const float* labels = (const float*)d_in[3];
    const int* hard_assign   = (const int*)d_in[4];
    const int* cached_groups = (const int*)d_in[5];
    const int* group_sizes   = (const int*)d_in[6];

    const int B = in_sizes[0] / DIMS;
    const int N = in_sizes[1] / DIMS;
    const int P = in_sizes[6];
    const int MAXG = in_sizes[5] / P;

    // slice_c: candidates per scoring block, multiple of 16
    int slice_c = (MAXG + SLICES - 1) / SLICES;
    slice_c = (slice_c + 15) & ~15;
    if (slice_c > 512) slice_c = 512;  // LDS cap (MAXG<=4096)

    float* inv_norm = (float*)d_ws;            // N floats
    float* sims     = inv_norm + N;            // B*MAXG floats

    key_norm_kernel<<<(N + 15) / 16, 256, 0, stream>>>(keys, inv_norm, N);

    score_kernel<<<B * SLICES, 256, 0, stream>>>(
        query, keys, hard_assign, cached_groups, inv_norm, sims, MAXG, slice_c);

    topk_gather_kernel<<<B, 256, 0, stream>>>(
        keys, vals, labels, hard_assign, cached_groups, group_sizes, sims,
        (float*)d_out, B, MAXG);
}

// Round 3
// 69.585 us; speedup vs baseline: 1.8258x; 1.3689x over previous
//
#include <hip/hip_runtime.h>

#define DIMS 128
#define KTOP 16
#define SMAX 2048     // max MAXG supported by top-k kernel LDS path
#define CAND 128      // candidates per score block
#define QCHUNK 16     // queries held in registers per pass

__device__ __forceinline__ float dot8(float4 a0, float4 a1, float4 b0, float4 b1) {
    return a0.x*b0.x + a0.y*b0.y + a0.z*b0.z + a0.w*b0.w
         + a1.x*b1.x + a1.y*b1.y + a1.z*b1.z + a1.w*b1.w;
}

// ---------------- Kernel 0: bucket queries by partition ----------------
__global__ __launch_bounds__(256)
void bucket_kernel(const int* __restrict__ hard_assign,
                   int* __restrict__ qcount, int* __restrict__ qlist, int B)
{
    const int b = blockIdx.x * 256 + threadIdx.x;
    if (b < B) {
        const int p = hard_assign[b];
        const int slot = atomicAdd(&qcount[p], 1);
        qlist[(size_t)p * B + slot] = b;
    }
}

// ---------------- Kernel 1: score CAND candidates vs all queries of one partition ----
__global__ __launch_bounds__(256)
void score_kernel(const float* __restrict__ query,
                  const float* __restrict__ keys,
                  const int*   __restrict__ cached_groups,
                  const int*   __restrict__ qcount,
                  const int*   __restrict__ qlist,
                  float* __restrict__ sims,
                  int B, int N, int MAXG, int nslice)
{
    const int p = blockIdx.x / nslice;
    const int s = blockIdx.x % nslice;
    const int cnt = qcount[p];
    if (cnt == 0) return;

    const int t   = threadIdx.x;
    const int sub = t & 15;     // D-slice lane (8 floats each)
    const int grp = t >> 4;     // candidate subgroup 0..15

    __shared__ int   s_g[CAND];
    __shared__ float s_sim[QCHUNK][CAND + 1];   // +1 pad: conflict-free

    const int base = s * CAND;
    const int* gp = cached_groups + (size_t)p * MAXG;
    if (t < CAND) s_g[t] = (base + t < MAXG) ? gp[base + t] : -1;
    __syncthreads();

    const int* ql = qlist + (size_t)p * B;
    const int nchunk = (cnt + QCHUNK - 1) / QCHUNK;

    for (int c = 0; c < nchunk; ++c) {
        const int qbase = c * QCHUNK;
        const int qid0  = ql[qbase];            // always valid (cnt > qbase)
        // 16 query fragments in registers (same for all 16 candidate subgroups)
        float4 qf0[QCHUNK], qf1[QCHUNK];
        #pragma unroll
        for (int q = 0; q < QCHUNK; ++q) {
            int ii = qbase + q;
            int sq = (ii < cnt) ? ql[ii] : qid0;   // tail: duplicate q0 (write-masked)
            const float* qr = query + (size_t)sq * DIMS + sub * 8;
            qf0[q] = *(const float4*)(qr);
            qf1[q] = *(const float4*)(qr + 4);
        }

        const int iters = CAND / 16;
        for (int it = 0; it < iters; ++it) {
            const int j = it * 16 + grp;
            const int cand = s_g[j];
            int safe = cand < 0 ? 0 : cand;
            if (safe > N - 1) safe = N - 1;
            const float* kr = keys + (size_t)safe * DIMS + sub * 8;
            const float4 k0 = *(const float4*)(kr);
            const float4 k1 = *(const float4*)(kr + 4);

            float ks = dot8(k0, k1, k0, k1);
            float v[QCHUNK];
            #pragma unroll
            for (int q = 0; q < QCHUNK; ++q) v[q] = dot8(qf0[q], qf1[q], k0, k1);

            // key-norm: full butterfly over the 16 D-slice lanes
            #pragma unroll
            for (int m = 1; m < 16; m <<= 1) ks += __shfl_xor(ks, m, 64);

            // halving tree: 16 partial-dot sets -> lane sub owns query slot q==sub
            float a[8];
            {
                const bool bit = sub & 1;
                #pragma unroll
                for (int jj = 0; jj < 8; ++jj) {
                    float send = bit ? v[2*jj] : v[2*jj+1];
                    float recv = __shfl_xor(send, 1, 64);
                    float keep = bit ? v[2*jj+1] : v[2*jj];
                    a[jj] = keep + recv;
                }
            }
            float cc[4];
            {
                const bool bit = (sub >> 1) & 1;
                #pragma unroll
                for (int jj = 0; jj < 4; ++jj) {
                    float send = bit ? a[2*jj] : a[2*jj+1];
                    float recv = __shfl_xor(send, 2, 64);
                    float keep = bit ? a[2*jj+1] : a[2*jj];
                    cc[jj] = keep + recv;
                }
            }
            float dd[2];
            {
                const bool bit = (sub >> 2) & 1;
                #pragma unroll
                for (int jj = 0; jj < 2; ++jj) {
                    float send = bit ? cc[2*jj] : cc[2*jj+1];
                    float recv = __shfl_xor(send, 4, 64);
                    float keep = bit ? cc[2*jj+1] : cc[2*jj];
                    dd[jj] = keep + recv;
                }
            }
            float e;
            {
                const bool bit = (sub >> 3) & 1;
                float send = bit ? dd[0] : dd[1];
                float recv = __shfl_xor(send, 8, 64);
                float keep = bit ? dd[1] : dd[0];
                e = keep + recv;
            }

            s_sim[sub][j] = (cand >= 0)
                ? e * (1.0f / fmaxf(sqrtf(ks), 1e-12f))
                : -1.0e9f;
        }
        __syncthreads();

        // coalesced flush: one row per valid query of this chunk
        for (int q = 0; q < QCHUNK; ++q) {
            const int ii = qbase + q;
            if (ii >= cnt) break;
            const int b = ql[ii];
            float* dst = sims + (size_t)b * MAXG + base;
            for (int x = t; x < CAND; x += 256)
                if (base + x < MAXG) dst[x] = s_sim[q][x];
        }
        if (c + 1 < nchunk) __syncthreads();
    }
}

// ---------------- Kernel 2: top-16 per query + output gather ----------------
__global__ __launch_bounds__(256)
void topk_gather_kernel(const float* __restrict__ keys,
                        const float* __restrict__ vals,
                        const float* __restrict__ labels,
                        const int*   __restrict__ hard_assign,
                        const int*   __restrict__ cached_groups,
                        const int*   __restrict__ group_sizes,
                        const float* __restrict__ sims,
                        float* __restrict__ out,
                        int B, int MAXG)
{
    const int b = blockIdx.x, t = threadIdx.x;
    const int sub = t & 15, cg = t >> 4;

    __shared__ unsigned long long s_red[4];
    __shared__ unsigned long long s_win;
    __shared__ int s_wing[KTOP];

    const int p = hard_assign[b];
    const int grp = group_sizes[p];
    const bool normal = (grp >= KTOP);
    const int* gptr = cached_groups + (size_t)p * MAXG;
    const float* simrow = sims + (size_t)b * MAXG;

    // pack (value, slot): larger value wins; ties -> smaller slot wins
    unsigned long long mk[SMAX / 256];
    #pragma unroll
    for (int j = 0; j < SMAX / 256; ++j) {
        const int g = j * 256 + t;
        const float v = (g < MAXG) ? simrow[g] : -3.0e38f;
        unsigned u = __float_as_uint(v);
        u = (u & 0x80000000u) ? ~u : (u | 0x80000000u);
        mk[j] = ((unsigned long long)u << 32) | (unsigned)(0xFFFFFFFFu - (unsigned)g);
    }

    for (int s = 0; s < KTOP; ++s) {
        unsigned long long m = mk[0];
        #pragma unroll
        for (int j = 1; j < SMAX / 256; ++j) m = (mk[j] > m) ? mk[j] : m;
        #pragma unroll
        for (int off = 1; off < 64; off <<= 1) {
            unsigned long long o = __shfl_xor(m, off, 64);
            m = (o > m) ? o : m;
        }
        if ((t & 63) == 0) s_red[t >> 6] = m;
        __syncthreads();
        if (t == 0) {
            unsigned long long w = s_red[0];
            if (s_red[1] > w) w = s_red[1];
            if (s_red[2] > w) w = s_red[2];
            if (s_red[3] > w) w = s_red[3];
            s_win = w;
            s_wing[s] = (int)(0xFFFFFFFFu - (unsigned)(w & 0xFFFFFFFFull));
        }
        __syncthreads();
        const unsigned long long w = s_win;
        #pragma unroll
        for (int j = 0; j < SMAX / 256; ++j) if (mk[j] == w) mk[j] = 0ull;
    }

    const int g    = s_wing[cg];
    const int cand = gptr[g];
    const int idx  = cand < 0 ? 0 : cand;

    const size_t BK = (size_t)B * KTOP;
    float* out_nk = out;
    float* out_nv = out + BK * DIMS;
    float* out_nl = out + 2 * BK * DIMS;
    float* out_id = out_nl + BK;

    const size_t od = ((size_t)b * KTOP + cg) * DIMS + sub * 8;
    if (normal) {
        const float* kr = keys + (size_t)idx * DIMS + sub * 8;
        const float* vr = vals + (size_t)idx * DIMS + sub * 8;
        *(float4*)(out_nk + od)     = *(const float4*)(kr);
        *(float4*)(out_nk + od + 4) = *(const float4*)(kr + 4);
        *(float4*)(out_nv + od)     = *(const float4*)(vr);
        *(float4*)(out_nv + od + 4) = *(const float4*)(vr + 4);
        if (sub == 0) {
            out_nl[(size_t)b * KTOP + cg] = labels[idx];
            out_id[(size_t)b * KTOP + cg] = (float)idx;
        }
    } else {
        const float4 z = make_float4(0.f, 0.f, 0.f, 0.f);
        *(float4*)(out_nk + od)     = z;
        *(float4*)(out_nk + od + 4) = z;
        *(float4*)(out_nv + od)     = z;
        *(float4*)(out_nv + od + 4) = z;
        if (sub == 0) {
            out_nl[(size_t)b * KTOP + cg] = 0.0f;
            out_id[(size_t)b * KTOP + cg] = 0.0f;
        }
    }
}

extern "C" void kernel_launch(void* const* d_in, const int* in_sizes, int n_in,
                              void* d_out, int out_size, void* d_ws, size_t ws_size,
                              hipStream_t stream) {
    const float* query  = (const float*)d_in[0];
    const float* keys   = (const float*)d_in[1];
    const float* vals   = (const float*)d_in[2];
    const float* labels = (const float*)d_in[3];
    const int* hard_assign   = (const int*)d_in[4];
    const int* cached_groups = (const int*)d_in[5];
    const int* group_sizes   = (const int*)d_in[6];

    const int B = in_sizes[0] / DIMS;
    const int N = in_sizes[1] / DIMS;
    const int P = in_sizes[6];
    const int MAXG = in_sizes[5] / P;
    const int nslice = (MAXG + CAND - 1) / CAND;

    float* sims  = (float*)d_ws;                          // B*MAXG floats
    int* qcount  = (int*)((char*)d_ws + (size_t)B * MAXG * 4);  // P ints
    int* qlist   = qcount + P;                            // P*B ints

    hipMemsetAsync(qcount, 0, P * sizeof(int), stream);

    bucket_kernel<<<(B + 255) / 256, 256, 0, stream>>>(hard_assign, qcount, qlist, B);

    score_kernel<<<P * nslice, 256, 0, stream>>>(
        query, keys, cached_groups, qcount, qlist, sims, B, N, MAXG, nslice);

    topk_gather_kernel<<<B, 256, 0, stream>>>(
        keys, vals, labels, hard_assign, cached_groups, group_sizes, sims,
        (float*)d_out, B, MAXG);
}

// Round 4
// 68.022 us; speedup vs baseline: 1.8677x; 1.0230x over previous
//
#include <hip/hip_runtime.h>

#define DIMS 128
#define KTOP 16
#define SMAX 2048     // max MAXG supported by top-k kernel
#define CAND 128      // candidates per score block
#define QCHUNK 8      // queries held in registers per pass (64 VGPRs)
#define CHSPLIT 4     // chunk-parallel blocks per (partition, slice)

__device__ __forceinline__ float dot8(float4 a0, float4 a1, float4 b0, float4 b1) {
    return a0.x*b0.x + a0.y*b0.y + a0.z*b0.z + a0.w*b0.w
         + a1.x*b1.x + a1.y*b1.y + a1.z*b1.z + a1.w*b1.w;
}

__device__ __forceinline__ unsigned long long packsim(float v, int g) {
    unsigned u = __float_as_uint(v);
    u = (u & 0x80000000u) ? ~u : (u | 0x80000000u);
    return ((unsigned long long)u << 32) | (unsigned)(0xFFFFFFFFu - (unsigned)g);
}

// ---------------- Kernel 0: bucket queries by partition ----------------
__global__ __launch_bounds__(256)
void bucket_kernel(const int* __restrict__ hard_assign,
                   int* __restrict__ qcount, int* __restrict__ qlist, int B)
{
    const int b = blockIdx.x * 256 + threadIdx.x;
    if (b < B) {
        const int p = hard_assign[b];
        const int slot = atomicAdd(&qcount[p], 1);
        qlist[(size_t)p * B + slot] = b;
    }
}

// ---------------- Kernel 1: score slice of candidates vs one query chunk ----
__global__ __launch_bounds__(256)
void score_kernel(const float* __restrict__ query,
                  const float* __restrict__ keys,
                  const int*   __restrict__ cached_groups,
                  const int*   __restrict__ qcount,
                  const int*   __restrict__ qlist,
                  float* __restrict__ sims,
                  int B, int N, int MAXG, int nslice)
{
    const int c0 = blockIdx.x % CHSPLIT;
    const int ps = blockIdx.x / CHSPLIT;
    const int p  = ps / nslice;
    const int s  = ps % nslice;
    const int cnt = qcount[p];
    if (c0 * QCHUNK >= cnt) return;          // no chunk for this block

    const int t   = threadIdx.x;
    const int sub = t & 15;     // D-slice lane (8 floats each)
    const int grp = t >> 4;     // candidate subgroup 0..15

    __shared__ int   s_g[CAND];
    __shared__ float s_sim[QCHUNK][CAND + 8];   // +8 pad: 2-way max on store

    const int base = s * CAND;
    const int* gp = cached_groups + (size_t)p * MAXG;
    if (t < CAND) s_g[t] = (base + t < MAXG) ? gp[base + t] : -1;
    __syncthreads();

    const int* ql = qlist + (size_t)p * B;

    for (int c = c0; c * QCHUNK < cnt; c += CHSPLIT) {
        const int qbase = c * QCHUNK;
        // 8 query fragments in registers (shared by all candidate subgroups)
        float4 qf0[QCHUNK], qf1[QCHUNK];
        #pragma unroll
        for (int q = 0; q < QCHUNK; ++q) {
            int ii = qbase + q;
            int iic = (ii < cnt) ? ii : qbase;      // tail: duplicate (write-masked)
            int sq = ql[iic];
            const float* qr = query + (size_t)sq * DIMS + sub * 8;
            qf0[q] = *(const float4*)(qr);
            qf1[q] = *(const float4*)(qr + 4);
        }

        // prefetch first candidate row
        int candn = s_g[grp];
        {
            int sf = candn < 0 ? 0 : (candn > N - 1 ? N - 1 : candn);
            const float* kr = keys + (size_t)sf * DIMS + sub * 8;
            // loads issued here, consumed next
            qf0[0].x += 0.0f; // no-op to keep ordering trivial (compiler schedules)
        }
        int sf0 = candn < 0 ? 0 : (candn > N - 1 ? N - 1 : candn);
        const float* kr0 = keys + (size_t)sf0 * DIMS + sub * 8;
        float4 nk0 = *(const float4*)(kr0);
        float4 nk1 = *(const float4*)(kr0 + 4);

        #pragma unroll 4
        for (int it = 0; it < CAND / 16; ++it) {
            const int j = it * 16 + grp;
            const int candc = candn;
            const float4 k0 = nk0, k1 = nk1;

            if (it + 1 < CAND / 16) {               // prefetch next row
                candn = s_g[(it + 1) * 16 + grp];
                int sf = candn < 0 ? 0 : (candn > N - 1 ? N - 1 : candn);
                const float* kr = keys + (size_t)sf * DIMS + sub * 8;
                nk0 = *(const float4*)(kr);
                nk1 = *(const float4*)(kr + 4);
            }

            float ks = dot8(k0, k1, k0, k1);
            float v[QCHUNK];
            #pragma unroll
            for (int q = 0; q < QCHUNK; ++q) v[q] = dot8(qf0[q], qf1[q], k0, k1);

            #pragma unroll
            for (int m = 1; m < 16; m <<= 1) ks += __shfl_xor(ks, m, 64);

            // halving tree: 8 partial sets over 16 lanes -> lane sub&7 owns q
            float a[4];
            {
                const bool bit = sub & 1;
                #pragma unroll
                for (int jj = 0; jj < 4; ++jj) {
                    float send = bit ? v[2*jj] : v[2*jj+1];
                    float recv = __shfl_xor(send, 1, 64);
                    float keep = bit ? v[2*jj+1] : v[2*jj];
                    a[jj] = keep + recv;
                }
            }
            float cc[2];
            {
                const bool bit = (sub >> 1) & 1;
                #pragma unroll
                for (int jj = 0; jj < 2; ++jj) {
                    float send = bit ? a[2*jj] : a[2*jj+1];
                    float recv = __shfl_xor(send, 2, 64);
                    float keep = bit ? a[2*jj+1] : a[2*jj];
                    cc[jj] = keep + recv;
                }
            }
            float dd;
            {
                const bool bit = (sub >> 2) & 1;
                float send = bit ? cc[0] : cc[1];
                float recv = __shfl_xor(send, 4, 64);
                float keep = bit ? cc[1] : cc[0];
                dd = keep + recv;
            }
            float e = dd + __shfl_xor(dd, 8, 64);

            if (sub < QCHUNK)
                s_sim[sub][j] = (candc >= 0)
                    ? e * (1.0f / fmaxf(sqrtf(ks), 1e-12f))
                    : -1.0e9f;
        }
        __syncthreads();

        // coalesced flush
        for (int q = 0; q < QCHUNK; ++q) {
            const int ii = qbase + q;
            if (ii >= cnt) break;
            const int b = ql[ii];
            float* dst = sims + (size_t)b * MAXG + base;
            for (int x = t; x < CAND; x += 256)
                if (base + x < MAXG) dst[x] = s_sim[q][x];
        }
        __syncthreads();
    }
}

// ---------------- Kernel 2: top-16 per query + output gather ----------------
__global__ __launch_bounds__(256)
void topk_gather_kernel(const float* __restrict__ keys,
                        const float* __restrict__ vals,
                        const float* __restrict__ labels,
                        const int*   __restrict__ hard_assign,
                        const int*   __restrict__ cached_groups,
                        const int*   __restrict__ group_sizes,
                        const float* __restrict__ sims,
                        float* __restrict__ out,
                        int B, int MAXG)
{
    const int b = blockIdx.x, t = threadIdx.x;
    const int lane = t & 63, w = t >> 6;
    const int sub = t & 15, cg = t >> 4;

    __shared__ unsigned long long s_merge[64];
    __shared__ int s_wing[KTOP];

    const int p = hard_assign[b];
    const int grpsz = group_sizes[p];
    const bool normal = (grpsz >= KTOP);
    const int* gptr = cached_groups + (size_t)p * MAXG;
    const float* simrow = sims + (size_t)b * MAXG;

    // phase A: wave-local top-16 of 512 values, shuffle-only
    unsigned long long mk[SMAX / 256];
    #pragma unroll
    for (int j = 0; j < SMAX / 256; ++j) {
        const int g = w * (SMAX / 4) + j * 64 + lane;     // coalesced per wave
        const float v = (g < MAXG) ? simrow[g] : -3.0e38f;
        mk[j] = packsim(v, g);
    }
    #pragma unroll 1
    for (int r = 0; r < KTOP; ++r) {
        unsigned long long m = mk[0];
        #pragma unroll
        for (int j = 1; j < SMAX / 256; ++j) m = (mk[j] > m) ? mk[j] : m;
        #pragma unroll
        for (int off = 1; off < 64; off <<= 1) {
            unsigned long long o = __shfl_xor(m, off, 64);
            m = (o > m) ? o : m;
        }
        if (lane == 0) s_merge[w * KTOP + r] = m;
        #pragma unroll
        for (int j = 0; j < SMAX / 256; ++j) if (mk[j] == m) mk[j] = 0ull;
    }
    __syncthreads();

    // phase B: wave 0 merges 64 survivors -> global top-16 in order
    if (w == 0) {
        unsigned long long u = s_merge[lane];
        #pragma unroll 1
        for (int r = 0; r < KTOP; ++r) {
            unsigned long long m = u;
            #pragma unroll
            for (int off = 1; off < 64; off <<= 1) {
                unsigned long long o = __shfl_xor(m, off, 64);
                m = (o > m) ? o : m;
            }
            if (lane == 0)
                s_wing[r] = (int)(0xFFFFFFFFu - (unsigned)(m & 0xFFFFFFFFull));
            if (u == m) u = 0ull;
        }
    }
    __syncthreads();

    // outputs: group cg handles winner #cg
    const int g    = s_wing[cg];
    const int cand = gptr[g];
    const int idx  = cand < 0 ? 0 : cand;

    const size_t BK = (size_t)B * KTOP;
    float* out_nk = out;
    float* out_nv = out + BK * DIMS;
    float* out_nl = out + 2 * BK * DIMS;
    float* out_id = out_nl + BK;

    const size_t od = ((size_t)b * KTOP + cg) * DIMS + sub * 8;
    if (normal) {
        const float* kr = keys + (size_t)idx * DIMS + sub * 8;
        const float* vr = vals + (size_t)idx * DIMS + sub * 8;
        *(float4*)(out_nk + od)     = *(const float4*)(kr);
        *(float4*)(out_nk + od + 4) = *(const float4*)(kr + 4);
        *(float4*)(out_nv + od)     = *(const float4*)(vr);
        *(float4*)(out_nv + od + 4) = *(const float4*)(vr + 4);
        if (sub == 0) {
            out_nl[(size_t)b * KTOP + cg] = labels[idx];
            out_id[(size_t)b * KTOP + cg] = (float)idx;
        }
    } else {
        const float4 z = make_float4(0.f, 0.f, 0.f, 0.f);
        *(float4*)(out_nk + od)     = z;
        *(float4*)(out_nk + od + 4) = z;
        *(float4*)(out_nv + od)     = z;
        *(float4*)(out_nv + od + 4) = z;
        if (sub == 0) {
            out_nl[(size_t)b * KTOP + cg] = 0.0f;
            out_id[(size_t)b * KTOP + cg] = 0.0f;
        }
    }
}

extern "C" void kernel_launch(void* const* d_in, const int* in_sizes, int n_in,
                              void* d_out, int out_size, void* d_ws, size_t ws_size,
                              hipStream_t stream) {
    const float* query  = (const float*)d_in[0];
    const float* keys   = (const float*)d_in[1];
    const float* vals   = (const float*)d_in[2];
    const float* labels = (const float*)d_in[3];
    const int* hard_assign   = (const int*)d_in[4];
    const int* cached_groups = (const int*)d_in[5];
    const int* group_sizes   = (const int*)d_in[6];

    const int B = in_sizes[0] / DIMS;
    const int N = in_sizes[1] / DIMS;
    const int P = in_sizes[6];
    const int MAXG = in_sizes[5] / P;
    const int nslice = (MAXG + CAND - 1) / CAND;

    float* sims  = (float*)d_ws;                                // B*MAXG floats
    int* qcount  = (int*)((char*)d_ws + (size_t)B * MAXG * 4);  // P ints
    int* qlist   = qcount + P;                                  // P*B ints

    hipMemsetAsync(qcount, 0, P * sizeof(int), stream);

    bucket_kernel<<<(B + 255) / 256, 256, 0, stream>>>(hard_assign, qcount, qlist, B);

    score_kernel<<<P * nslice * CHSPLIT, 256, 0, stream>>>(
        query, keys, cached_groups, qcount, qlist, sims, B, N, MAXG, nslice);

    topk_gather_kernel<<<B, 256, 0, stream>>>(
        keys, vals, labels, hard_assign, cached_groups, group_sizes, sims,
        (float*)d_out, B, MAXG);
}

// Round 5
// 65.102 us; speedup vs baseline: 1.9515x; 1.0448x over previous
//
#include <hip/hip_runtime.h>

#define DIMS 128
#define KTOP 16
#define SMAX 2048     // max MAXG supported by top-k kernel
#define SLICE 64      // candidates staged per score block
#define SKP 132       // padded LDS row stride in floats (128+4: kills cross-group conflicts)
#define QCHUNK 8      // queries per compute pass (64 VGPRs of query fragments)

__device__ __forceinline__ float dot8(float4 a0, float4 a1, float4 b0, float4 b1) {
    return a0.x*b0.x + a0.y*b0.y + a0.z*b0.z + a0.w*b0.w
         + a1.x*b1.x + a1.y*b1.y + a1.z*b1.z + a1.w*b1.w;
}

__device__ __forceinline__ unsigned long long packsim(float v, int g) {
    unsigned u = __float_as_uint(v);
    u = (u & 0x80000000u) ? ~u : (u | 0x80000000u);
    return ((unsigned long long)u << 32) | (unsigned)(0xFFFFFFFFu - (unsigned)g);
}

// ---------------- Kernel 0: bucket queries by partition ----------------
__global__ __launch_bounds__(256)
void bucket_kernel(const int* __restrict__ hard_assign,
                   int* __restrict__ qcount, int* __restrict__ qlist, int B)
{
    const int b = blockIdx.x * 256 + threadIdx.x;
    if (b < B) {
        const int p = hard_assign[b];
        const int slot = atomicAdd(&qcount[p], 1);
        qlist[(size_t)p * B + slot] = b;
    }
}

// ---- Kernel 1: stage 64 candidate rows in LDS, score all queries of p ----
__global__ __launch_bounds__(256)
void score_kernel(const float* __restrict__ query,
                  const float* __restrict__ keys,
                  const int*   __restrict__ cached_groups,
                  const int*   __restrict__ qcount,
                  const int*   __restrict__ qlist,
                  float* __restrict__ sims,
                  int B, int N, int MAXG, int nslice)
{
    const int p = blockIdx.x / nslice;
    const int s = blockIdx.x % nslice;
    const int cnt = qcount[p];
    if (cnt == 0) return;

    const int t   = threadIdx.x;
    const int sub = t & 15;     // D-slice lane (8 floats each)
    const int grp = t >> 4;     // candidate subgroup 0..15

    __shared__ int   s_g[SLICE];
    __shared__ float s_key[SLICE * SKP];
    __shared__ float s_sim[QCHUNK][SLICE + 4];

    const int base = s * SLICE;
    const int* gp = cached_groups + (size_t)p * MAXG;
    if (t < SLICE) s_g[t] = (base + t < MAXG) ? gp[base + t] : -1;
    __syncthreads();

    // phase 1: gather 64 rows -> LDS. 8 independent loads per lane (deep MLP).
    {
        float4 r0[4], r1[4];
        #pragma unroll
        for (int i = 0; i < 4; ++i) {
            const int j = i * 16 + grp;
            const int cand = s_g[j];
            const int sf = cand < 0 ? 0 : (cand > N - 1 ? N - 1 : cand);
            const float* kr = keys + (size_t)sf * DIMS + sub * 8;
            r0[i] = *(const float4*)(kr);
            r1[i] = *(const float4*)(kr + 4);
        }
        #pragma unroll
        for (int i = 0; i < 4; ++i) {
            const int j = i * 16 + grp;
            *(float4*)&s_key[j * SKP + sub * 8]     = r0[i];
            *(float4*)&s_key[j * SKP + sub * 8 + 4] = r1[i];
        }
    }
    __syncthreads();

    const int* ql = qlist + (size_t)p * B;
    const int nchunk = (cnt + QCHUNK - 1) / QCHUNK;

    for (int c = 0; c < nchunk; ++c) {
        const int qbase = c * QCHUNK;
        // 8 query fragments in registers (shared across candidate subgroups)
        float4 qf0[QCHUNK], qf1[QCHUNK];
        #pragma unroll
        for (int q = 0; q < QCHUNK; ++q) {
            const int ii = qbase + q;
            const int iic = (ii < cnt) ? ii : qbase;   // tail: dup (write-masked)
            const int sq = ql[iic];
            const float* qr = query + (size_t)sq * DIMS + sub * 8;
            qf0[q] = *(const float4*)(qr);
            qf1[q] = *(const float4*)(qr + 4);
        }

        #pragma unroll
        for (int it = 0; it < SLICE / 16; ++it) {
            const int j = it * 16 + grp;
            const float4 k0 = *(const float4*)&s_key[j * SKP + sub * 8];
            const float4 k1 = *(const float4*)&s_key[j * SKP + sub * 8 + 4];

            float ks = dot8(k0, k1, k0, k1);
            float v[QCHUNK];
            #pragma unroll
            for (int q = 0; q < QCHUNK; ++q) v[q] = dot8(qf0[q], qf1[q], k0, k1);

            #pragma unroll
            for (int m = 1; m < 16; m <<= 1) ks += __shfl_xor(ks, m, 64);

            // halving tree: 8 partial sets over 16 lanes -> lane sub (<8) owns q=sub
            float a[4];
            {
                const bool bit = sub & 1;
                #pragma unroll
                for (int jj = 0; jj < 4; ++jj) {
                    float send = bit ? v[2*jj] : v[2*jj+1];
                    float recv = __shfl_xor(send, 1, 64);
                    float keep = bit ? v[2*jj+1] : v[2*jj];
                    a[jj] = keep + recv;
                }
            }
            float cc[2];
            {
                const bool bit = (sub >> 1) & 1;
                #pragma unroll
                for (int jj = 0; jj < 2; ++jj) {
                    float send = bit ? a[2*jj] : a[2*jj+1];
                    float recv = __shfl_xor(send, 2, 64);
                    float keep = bit ? a[2*jj+1] : a[2*jj];
                    cc[jj] = keep + recv;
                }
            }
            float dd;
            {
                const bool bit = (sub >> 2) & 1;
                float send = bit ? cc[0] : cc[1];
                float recv = __shfl_xor(send, 4, 64);
                float keep = bit ? cc[1] : cc[0];
                dd = keep + recv;
            }
            const float e = dd + __shfl_xor(dd, 8, 64);

            if (sub < QCHUNK)
                s_sim[sub][j] = (s_g[j] >= 0)
                    ? e * (1.0f / fmaxf(sqrtf(ks), 1e-12f))
                    : -1.0e9f;
        }
        __syncthreads();

        // flush: each wave writes one query row of 64 floats, two passes
        #pragma unroll
        for (int half = 0; half < 2; ++half) {
            const int q  = half * 4 + (t >> 6);
            const int ii = qbase + q;
            if (ii < cnt) {
                const int b = ql[ii];
                const int x = t & 63;
                if (base + x < MAXG)
                    sims[(size_t)b * MAXG + base + x] = s_sim[q][x];
            }
        }
        __syncthreads();
    }
}

// ---------------- Kernel 2: top-16 per query + output gather ----------------
__global__ __launch_bounds__(256)
void topk_gather_kernel(const float* __restrict__ keys,
                        const float* __restrict__ vals,
                        const float* __restrict__ labels,
                        const int*   __restrict__ hard_assign,
                        const int*   __restrict__ cached_groups,
                        const int*   __restrict__ group_sizes,
                        const float* __restrict__ sims,
                        float* __restrict__ out,
                        int B, int MAXG)
{
    const int b = blockIdx.x, t = threadIdx.x;
    const int lane = t & 63, w = t >> 6;
    const int sub = t & 15, cg = t >> 4;

    __shared__ unsigned long long s_merge[64];
    __shared__ int s_wing[KTOP];

    const int p = hard_assign[b];
    const int grpsz = group_sizes[p];
    const bool normal = (grpsz >= KTOP);
    const int* gptr = cached_groups + (size_t)p * MAXG;
    const float* simrow = sims + (size_t)b * MAXG;

    // phase A: wave-local top-16 of 512 values, shuffle-only
    unsigned long long mk[SMAX / 256];
    #pragma unroll
    for (int j = 0; j < SMAX / 256; ++j) {
        const int g = w * (SMAX / 4) + j * 64 + lane;
        const float v = (g < MAXG) ? simrow[g] : -3.0e38f;
        mk[j] = packsim(v, g);
    }
    #pragma unroll 1
    for (int r = 0; r < KTOP; ++r) {
        unsigned long long m = mk[0];
        #pragma unroll
        for (int j = 1; j < SMAX / 256; ++j) m = (mk[j] > m) ? mk[j] : m;
        #pragma unroll
        for (int off = 1; off < 64; off <<= 1) {
            unsigned long long o = __shfl_xor(m, off, 64);
            m = (o > m) ? o : m;
        }
        if (lane == 0) s_merge[w * KTOP + r] = m;
        #pragma unroll
        for (int j = 0; j < SMAX / 256; ++j) if (mk[j] == m) mk[j] = 0ull;
    }
    __syncthreads();

    // phase B: wave 0 merges 64 survivors -> global top-16 in order
    if (w == 0) {
        unsigned long long u = s_merge[lane];
        #pragma unroll 1
        for (int r = 0; r < KTOP; ++r) {
            unsigned long long m = u;
            #pragma unroll
            for (int off = 1; off < 64; off <<= 1) {
                unsigned long long o = __shfl_xor(m, off, 64);
                m = (o > m) ? o : m;
            }
            if (lane == 0)
                s_wing[r] = (int)(0xFFFFFFFFu - (unsigned)(m & 0xFFFFFFFFull));
            if (u == m) u = 0ull;
        }
    }
    __syncthreads();

    // outputs: group cg handles winner #cg
    const int g    = s_wing[cg];
    const int cand = gptr[g];
    const int idx  = cand < 0 ? 0 : cand;

    const size_t BK = (size_t)B * KTOP;
    float* out_nk = out;
    float* out_nv = out + BK * DIMS;
    float* out_nl = out + 2 * BK * DIMS;
    float* out_id = out_nl + BK;

    const size_t od = ((size_t)b * KTOP + cg) * DIMS + sub * 8;
    if (normal) {
        const float* kr = keys + (size_t)idx * DIMS + sub * 8;
        const float* vr = vals + (size_t)idx * DIMS + sub * 8;
        *(float4*)(out_nk + od)     = *(const float4*)(kr);
        *(float4*)(out_nk + od + 4) = *(const float4*)(kr + 4);
        *(float4*)(out_nv + od)     = *(const float4*)(vr);
        *(float4*)(out_nv + od + 4) = *(const float4*)(vr + 4);
        if (sub == 0) {
            out_nl[(size_t)b * KTOP + cg] = labels[idx];
            out_id[(size_t)b * KTOP + cg] = (float)idx;
        }
    } else {
        const float4 z = make_float4(0.f, 0.f, 0.f, 0.f);
        *(float4*)(out_nk + od)     = z;
        *(float4*)(out_nk + od + 4) = z;
        *(float4*)(out_nv + od)     = z;
        *(float4*)(out_nv + od + 4) = z;
        if (sub == 0) {
            out_nl[(size_t)b * KTOP + cg] = 0.0f;
            out_id[(size_t)b * KTOP + cg] = 0.0f;
        }
    }
}

extern "C" void kernel_launch(void* const* d_in, const int* in_sizes, int n_in,
                              void* d_out, int out_size, void* d_ws, size_t ws_size,
                              hipStream_t stream) {
    const float* query  = (const float*)d_in[0];
    const float* keys   = (const float*)d_in[1];
    const float* vals   = (const float*)d_in[2];
    const float* labels = (const float*)d_in[3];
    const int* hard_assign   = (const int*)d_in[4];
    const int* cached_groups = (const int*)d_in[5];
    const int* group_sizes   = (const int*)d_in[6];

    const int B = in_sizes[0] / DIMS;
    const int N = in_sizes[1] / DIMS;
    const int P = in_sizes[6];
    const int MAXG = in_sizes[5] / P;
    const int nslice = (MAXG + SLICE - 1) / SLICE;

    float* sims  = (float*)d_ws;                                // B*MAXG floats
    int* qcount  = (int*)((char*)d_ws + (size_t)B * MAXG * 4);  // P ints
    int* qlist   = qcount + P;                                  // P*B ints

    hipMemsetAsync(qcount, 0, P * sizeof(int), stream);

    bucket_kernel<<<(B + 255) / 256, 256, 0, stream>>>(hard_assign, qcount, qlist, B);

    score_kernel<<<P * nslice, 256, 0, stream>>>(
        query, keys, cached_groups, qcount, qlist, sims, B, N, MAXG, nslice);

    topk_gather_kernel<<<B, 256, 0, stream>>>(
        keys, vals, labels, hard_assign, cached_groups, group_sizes, sims,
        (float*)d_out, B, MAXG);
}

// Round 6
// 62.299 us; speedup vs baseline: 2.0393x; 1.0450x over previous
//
#include <hip/hip_runtime.h>

#define DIMS 128
#define KTOP 16
#define SMAX 2048     // max MAXG supported by top-k kernel
#define SLICE 32      // candidates staged per score block
#define SKP 132       // padded LDS row stride (balanced banks for b128 at sub*8)
#define QCHUNK 8      // queries per compute pass (64 VGPRs of query fragments)

__device__ __forceinline__ float dot8(float4 a0, float4 a1, float4 b0, float4 b1) {
    return a0.x*b0.x + a0.y*b0.y + a0.z*b0.z + a0.w*b0.w
         + a1.x*b1.x + a1.y*b1.y + a1.z*b1.z + a1.w*b1.w;
}

__device__ __forceinline__ unsigned long long packsim(float v, int g) {
    unsigned u = __float_as_uint(v);
    u = (u & 0x80000000u) ? ~u : (u | 0x80000000u);
    return ((unsigned long long)u << 32) | (unsigned)(0xFFFFFFFFu - (unsigned)g);
}

// ---------------- Kernel 0: zero + bucket queries, single block ----------------
__global__ __launch_bounds__(1024)
void bucket_kernel(const int* __restrict__ hard_assign,
                   int* __restrict__ qcount, int* __restrict__ qlist, int B, int P)
{
    const int t = threadIdx.x;
    for (int i = t; i < P; i += 1024) qcount[i] = 0;
    __syncthreads();
    for (int b = t; b < B; b += 1024) {
        const int p = hard_assign[b];
        const int slot = atomicAdd(&qcount[p], 1);
        qlist[(size_t)p * B + slot] = b;
    }
}

// ---- Kernel 1: stage 32 normalized rows in LDS, score all queries of p ----
__global__ __launch_bounds__(256, 4)
void score_kernel(const float* __restrict__ query,
                  const float* __restrict__ keys,
                  const int*   __restrict__ cached_groups,
                  const int*   __restrict__ qcount,
                  const int*   __restrict__ qlist,
                  float* __restrict__ sims,
                  int B, int N, int MAXG, int nslice)
{
    const int p = blockIdx.x / nslice;
    const int s = blockIdx.x % nslice;
    const int cnt = qcount[p];
    if (cnt == 0) return;

    const int t   = threadIdx.x;
    const int sub = t & 15;     // D-slice lane (8 floats each)
    const int grp = t >> 4;     // candidate subgroup 0..15

    __shared__ int   s_g[SLICE];
    __shared__ float s_key[SLICE * SKP];
    __shared__ float s_sim[QCHUNK][SLICE + 4];

    const int base = s * SLICE;
    const int* gp = cached_groups + (size_t)p * MAXG;
    if (t < SLICE) s_g[t] = (base + t < MAXG) ? gp[base + t] : -1;
    __syncthreads();

    // phase 1: gather 2 rows per lane-group (4 independent b128 loads),
    // L2-normalize in registers, store pre-scaled to LDS.
    {
        const int j0 = grp, j1 = 16 + grp;
        const int c0 = s_g[j0], c1 = s_g[j1];
        const int sf0 = c0 < 0 ? 0 : (c0 > N - 1 ? N - 1 : c0);
        const int sf1 = c1 < 0 ? 0 : (c1 > N - 1 ? N - 1 : c1);
        const float* kr0 = keys + (size_t)sf0 * DIMS + sub * 8;
        const float* kr1 = keys + (size_t)sf1 * DIMS + sub * 8;
        float4 a0 = *(const float4*)(kr0);
        float4 a1 = *(const float4*)(kr0 + 4);
        float4 b0 = *(const float4*)(kr1);
        float4 b1 = *(const float4*)(kr1 + 4);
        float ks0 = dot8(a0, a1, a0, a1);
        float ks1 = dot8(b0, b1, b0, b1);
        #pragma unroll
        for (int m = 1; m < 16; m <<= 1) {
            ks0 += __shfl_xor(ks0, m, 64);
            ks1 += __shfl_xor(ks1, m, 64);
        }
        const float i0 = 1.0f / fmaxf(sqrtf(ks0), 1e-12f);
        const float i1 = 1.0f / fmaxf(sqrtf(ks1), 1e-12f);
        a0.x *= i0; a0.y *= i0; a0.z *= i0; a0.w *= i0;
        a1.x *= i0; a1.y *= i0; a1.z *= i0; a1.w *= i0;
        b0.x *= i1; b0.y *= i1; b0.z *= i1; b0.w *= i1;
        b1.x *= i1; b1.y *= i1; b1.z *= i1; b1.w *= i1;
        *(float4*)&s_key[j0 * SKP + sub * 8]     = a0;
        *(float4*)&s_key[j0 * SKP + sub * 8 + 4] = a1;
        *(float4*)&s_key[j1 * SKP + sub * 8]     = b0;
        *(float4*)&s_key[j1 * SKP + sub * 8 + 4] = b1;
    }
    __syncthreads();

    const int* ql = qlist + (size_t)p * B;
    const int nchunk = (cnt + QCHUNK - 1) / QCHUNK;

    for (int c = 0; c < nchunk; ++c) {
        const int qbase = c * QCHUNK;
        // 8 query fragments in registers (launch_bounds(256,4) gives 128 VGPRs)
        float4 qf0[QCHUNK], qf1[QCHUNK];
        #pragma unroll
        for (int q = 0; q < QCHUNK; ++q) {
            const int ii = qbase + q;
            const int iic = (ii < cnt) ? ii : qbase;   // tail: dup (write-masked)
            const int sq = ql[iic];
            const float* qr = query + (size_t)sq * DIMS + sub * 8;
            qf0[q] = *(const float4*)(qr);
            qf1[q] = *(const float4*)(qr + 4);
        }

        #pragma unroll
        for (int it = 0; it < SLICE / 16; ++it) {
            const int j = it * 16 + grp;
            const float4 k0 = *(const float4*)&s_key[j * SKP + sub * 8];
            const float4 k1 = *(const float4*)&s_key[j * SKP + sub * 8 + 4];

            float v[QCHUNK];
            #pragma unroll
            for (int q = 0; q < QCHUNK; ++q) v[q] = dot8(qf0[q], qf1[q], k0, k1);

            // halving tree: 8 partial sets over 16 lanes -> lane sub (<8) owns q=sub
            float a[4];
            {
                const bool bit = sub & 1;
                #pragma unroll
                for (int jj = 0; jj < 4; ++jj) {
                    float send = bit ? v[2*jj] : v[2*jj+1];
                    float recv = __shfl_xor(send, 1, 64);
                    float keep = bit ? v[2*jj+1] : v[2*jj];
                    a[jj] = keep + recv;
                }
            }
            float cc[2];
            {
                const bool bit = (sub >> 1) & 1;
                #pragma unroll
                for (int jj = 0; jj < 2; ++jj) {
                    float send = bit ? a[2*jj] : a[2*jj+1];
                    float recv = __shfl_xor(send, 2, 64);
                    float keep = bit ? a[2*jj+1] : a[2*jj];
                    cc[jj] = keep + recv;
                }
            }
            float dd;
            {
                const bool bit = (sub >> 2) & 1;
                float send = bit ? cc[0] : cc[1];
                float recv = __shfl_xor(send, 4, 64);
                float keep = bit ? cc[1] : cc[0];
                dd = keep + recv;
            }
            const float e = dd + __shfl_xor(dd, 8, 64);

            if (sub < QCHUNK)
                s_sim[sub][j] = (s_g[j] >= 0) ? e : -1.0e9f;
        }
        __syncthreads();

        // flush: thread t writes one float; 128B contiguous per query row
        {
            const int q  = t >> 5;           // 0..7
            const int x  = t & 31;           // 0..31
            const int ii = qbase + q;
            if (ii < cnt && base + x < MAXG) {
                const int b = ql[ii];
                sims[(size_t)b * MAXG + base + x] = s_sim[q][x];
            }
        }
        __syncthreads();
    }
}

// ---------------- Kernel 2: top-16 per query + output gather ----------------
__global__ __launch_bounds__(256)
void topk_gather_kernel(const float* __restrict__ keys,
                        const float* __restrict__ vals,
                        const float* __restrict__ labels,
                        const int*   __restrict__ hard_assign,
                        const int*   __restrict__ cached_groups,
                        const int*   __restrict__ group_sizes,
                        const float* __restrict__ sims,
                        float* __restrict__ out,
                        int B, int MAXG)
{
    const int b = blockIdx.x, t = threadIdx.x;
    const int lane = t & 63, w = t >> 6;
    const int sub = t & 15, cg = t >> 4;

    __shared__ unsigned long long s_merge[64];
    __shared__ int s_wing[KTOP];

    const int p = hard_assign[b];
    const int grpsz = group_sizes[p];
    const bool normal = (grpsz >= KTOP);
    const int* gptr = cached_groups + (size_t)p * MAXG;
    const float* simrow = sims + (size_t)b * MAXG;

    // phase A: wave-local top-16 of 512 values, shuffle-only
    unsigned long long mk[SMAX / 256];
    #pragma unroll
    for (int j = 0; j < SMAX / 256; ++j) {
        const int g = w * (SMAX / 4) + j * 64 + lane;
        const float v = (g < MAXG) ? simrow[g] : -3.0e38f;
        mk[j] = packsim(v, g);
    }
    #pragma unroll 1
    for (int r = 0; r < KTOP; ++r) {
        unsigned long long m = mk[0];
        #pragma unroll
        for (int j = 1; j < SMAX / 256; ++j) m = (mk[j] > m) ? mk[j] : m;
        #pragma unroll
        for (int off = 1; off < 64; off <<= 1) {
            unsigned long long o = __shfl_xor(m, off, 64);
            m = (o > m) ? o : m;
        }
        if (lane == 0) s_merge[w * KTOP + r] = m;
        #pragma unroll
        for (int j = 0; j < SMAX / 256; ++j) if (mk[j] == m) mk[j] = 0ull;
    }
    __syncthreads();

    // phase B: wave 0 merges 64 survivors -> global top-16 in order
    if (w == 0) {
        unsigned long long u = s_merge[lane];
        #pragma unroll 1
        for (int r = 0; r < KTOP; ++r) {
            unsigned long long m = u;
            #pragma unroll
            for (int off = 1; off < 64; off <<= 1) {
                unsigned long long o = __shfl_xor(m, off, 64);
                m = (o > m) ? o : m;
            }
            if (lane == 0)
                s_wing[r] = (int)(0xFFFFFFFFu - (unsigned)(m & 0xFFFFFFFFull));
            if (u == m) u = 0ull;
        }
    }
    __syncthreads();

    // outputs: group cg handles winner #cg
    const int g    = s_wing[cg];
    const int cand = gptr[g];
    const int idx  = cand < 0 ? 0 : cand;

    const size_t BK = (size_t)B * KTOP;
    float* out_nk = out;
    float* out_nv = out + BK * DIMS;
    float* out_nl = out + 2 * BK * DIMS;
    float* out_id = out_nl + BK;

    const size_t od = ((size_t)b * KTOP + cg) * DIMS + sub * 8;
    if (normal) {
        const float* kr = keys + (size_t)idx * DIMS + sub * 8;
        const float* vr = vals + (size_t)idx * DIMS + sub * 8;
        *(float4*)(out_nk + od)     = *(const float4*)(kr);
        *(float4*)(out_nk + od + 4) = *(const float4*)(kr + 4);
        *(float4*)(out_nv + od)     = *(const float4*)(vr);
        *(float4*)(out_nv + od + 4) = *(const float4*)(vr + 4);
        if (sub == 0) {
            out_nl[(size_t)b * KTOP + cg] = labels[idx];
            out_id[(size_t)b * KTOP + cg] = (float)idx;
        }
    } else {
        const float4 z = make_float4(0.f, 0.f, 0.f, 0.f);
        *(float4*)(out_nk + od)     = z;
        *(float4*)(out_nk + od + 4) = z;
        *(float4*)(out_nv + od)     = z;
        *(float4*)(out_nv + od + 4) = z;
        if (sub == 0) {
            out_nl[(size_t)b * KTOP + cg] = 0.0f;
            out_id[(size_t)b * KTOP + cg] = 0.0f;
        }
    }
}

extern "C" void kernel_launch(void* const* d_in, const int* in_sizes, int n_in,
                              void* d_out, int out_size, void* d_ws, size_t ws_size,
                              hipStream_t stream) {
    const float* query  = (const float*)d_in[0];
    const float* keys   = (const float*)d_in[1];
    const float* vals   = (const float*)d_in[2];
    const float* labels = (const float*)d_in[3];
    const int* hard_assign   = (const int*)d_in[4];
    const int* cached_groups = (const int*)d_in[5];
    const int* group_sizes   = (const int*)d_in[6];

    const int B = in_sizes[0] / DIMS;
    const int N = in_sizes[1] / DIMS;
    const int P = in_sizes[6];
    const int MAXG = in_sizes[5] / P;
    const int nslice = (MAXG + SLICE - 1) / SLICE;

    float* sims  = (float*)d_ws;                                // B*MAXG floats
    int* qcount  = (int*)((char*)d_ws + (size_t)B * MAXG * 4);  // P ints
    int* qlist   = qcount + P;                                  // P*B ints

    bucket_kernel<<<1, 1024, 0, stream>>>(hard_assign, qcount, qlist, B, P);

    score_kernel<<<P * nslice, 256, 0, stream>>>(
        query, keys, cached_groups, qcount, qlist, sims, B, N, MAXG, nslice);

    topk_gather_kernel<<<B, 256, 0, stream>>>(
        keys, vals, labels, hard_assign, cached_groups, group_sizes, sims,
        (float*)d_out, B, MAXG);
}